// Round 3
// baseline (3727.506 us; speedup 1.0000x reference)
//
#include <hip/hip_runtime.h>
#include <stdint.h>
#include <math.h>

// jax.random threefry2x32, partitionable mode — verified bit-exact (round 1,
// absmax 0.0). DO NOT change any arithmetic in the decision chain:
// the fp32 fmaf chain order j=0..255, expf, compares are all load-bearing
// (round 2 proved even a correctly-rounded f64 field diverges: absmax 10).
#define PARTITIONABLE 1

namespace {

constexpr int kB = 4096;
constexpr int kN = 256;
constexpr int kSweeps = 200;
constexpr int kSamp = 8;                 // samples per block
constexpr int kBlocks = kB / kSamp;      // 512 blocks -> 8 waves/CU

typedef _Float16 half8 __attribute__((ext_vector_type(8)));

struct K2 { uint32_t a, b; };

__host__ __device__ constexpr uint32_t crotl(uint32_t x, int d) {
  return (x << d) | (x >> (32 - d));
}

__host__ __device__ constexpr K2 ctf(uint32_t k0, uint32_t k1, uint32_t c0, uint32_t c1) {
  uint32_t ks0 = k0, ks1 = k1, ks2 = k0 ^ k1 ^ 0x1BD11BDAu;
  uint32_t x0 = c0 + ks0, x1 = c1 + ks1;
  const int r0[4] = {13, 15, 26, 6};
  const int r1[4] = {17, 29, 16, 24};
  for (int i = 0; i < 4; ++i) { x0 += x1; x1 = crotl(x1, r0[i]); x1 ^= x0; }
  x0 += ks1; x1 += ks2 + 1u;
  for (int i = 0; i < 4; ++i) { x0 += x1; x1 = crotl(x1, r1[i]); x1 ^= x0; }
  x0 += ks2; x1 += ks0 + 2u;
  for (int i = 0; i < 4; ++i) { x0 += x1; x1 = crotl(x1, r0[i]); x1 ^= x0; }
  x0 += ks0; x1 += ks1 + 3u;
  for (int i = 0; i < 4; ++i) { x0 += x1; x1 = crotl(x1, r1[i]); x1 ^= x0; }
  x0 += ks1; x1 += ks2 + 4u;
  for (int i = 0; i < 4; ++i) { x0 += x1; x1 = crotl(x1, r0[i]); x1 ^= x0; }
  x0 += ks2; x1 += ks0 + 5u;
  return K2{x0, x1};
}

struct KeyTable {
  uint32_t s0k[2];
  uint32_t sk[kSweeps][4];   // per sweep: k1a,k1b (accept), k2a,k2b (mask)
};

constexpr KeyTable make_keys() {
  KeyTable t{};
  K2 root{0u, 42u};
#if PARTITIONABLE
  K2 k0 = ctf(root.a, root.b, 0u, 0u);
  K2 kl = ctf(root.a, root.b, 0u, 1u);
#else
  K2 p0 = ctf(root.a, root.b, 0u, 2u);
  K2 p1 = ctf(root.a, root.b, 1u, 3u);
  K2 k0{p0.a, p1.a};
  K2 kl{p0.b, p1.b};
#endif
  t.s0k[0] = k0.a; t.s0k[1] = k0.b;
  K2 k = kl;
  for (int s = 0; s < kSweeps; ++s) {
#if PARTITIONABLE
    K2 kn = ctf(k.a, k.b, 0u, 0u);
    K2 k1 = ctf(k.a, k.b, 0u, 1u);
    K2 k2 = ctf(k.a, k.b, 0u, 2u);
#else
    K2 q0 = ctf(k.a, k.b, 0u, 3u);
    K2 q1 = ctf(k.a, k.b, 1u, 4u);
    K2 q2 = ctf(k.a, k.b, 2u, 5u);
    K2 kn{q0.a, q1.a};
    K2 k1{q2.a, q0.b};
    K2 k2{q1.b, q2.b};
#endif
    t.sk[s][0] = k1.a; t.sk[s][1] = k1.b;
    t.sk[s][2] = k2.a; t.sk[s][3] = k2.b;
    k = kn;
  }
  return t;
}

__constant__ KeyTable g_keys = make_keys();

__device__ __forceinline__ uint32_t rng_bits32(uint32_t ka, uint32_t kb, uint32_t m) {
#if PARTITIONABLE
  K2 r = ctf(ka, kb, 0u, m);
  return r.a ^ r.b;
#else
  constexpr uint32_t H = (uint32_t)(kB * kN / 2);
  uint32_t p = (m < H) ? m : (m - H);
  K2 r = ctf(ka, kb, p, p + H);
  return (m < H) ? r.a : r.b;
#endif
}

__device__ __forceinline__ float bits_to_uniform(uint32_t bits) {
  return __uint_as_float((bits >> 9) | 0x3f800000u) - 1.0f;
}

__global__ void prep_kernel(const float* __restrict__ gamma,
                            float* __restrict__ jsym,
                            float* __restrict__ betas) {
  int e = blockIdx.x * blockDim.x + threadIdx.x;   // 0..65535
  int i = e / kN, j = e % kN;
  float v = 0.0f;
  if (i < j) v = gamma[i * kN + j];
  else if (i > j) v = gamma[j * kN + i];
  jsym[e] = v;
  if (e < kSweeps) {
    double l0 = log(0.1), l1 = log(5.0);
    betas[e] = (float)exp(l0 + (l1 - l0) * (double)e / (double)(kSweeps - 1));
  }
}

__global__ __launch_bounds__(256) void anneal_kernel(
    const float* __restrict__ thetas, const float* __restrict__ jsym,
    const float* __restrict__ betas, float* __restrict__ out) {
  // s as f16 (+-1.0 exact): one ds_read_b128 delivers 8 j per sample.
  __shared__ __align__(16) _Float16 sh16[kSamp][kN];
  __shared__ float sh_red[kSamp][4];

  const int i = threadIdx.x;           // spin index (lane+wave)
  const int b0 = blockIdx.x * kSamp;

  float th[kSamp], sreg[kSamp];
#pragma unroll
  for (int g = 0; g < kSamp; ++g) th[g] = thetas[(b0 + g) * kN + i];

#pragma unroll
  for (int g = 0; g < kSamp; ++g) {
    uint32_t m = (uint32_t)((b0 + g) * kN + i);
    float u = bits_to_uniform(rng_bits32(g_keys.s0k[0], g_keys.s0k[1], m));
    float sv = (u < 0.5f) ? 1.0f : -1.0f;
    sreg[g] = sv;
    sh16[g][i] = (_Float16)sv;
  }
  __syncthreads();

  for (int t = 0; t < kSweeps; ++t) {
    const float beta = betas[t];

    float acc[kSamp];
#pragma unroll
    for (int g = 0; g < kSamp; ++g) acc[g] = 0.0f;

    // Chain: acc_i = sum_j J[i][j]*s[j], j ascending, one fp32 fma per term.
    // J[i][j] loaded as J[j][i] (exact symmetry) -> coalesced 256B/wave.
    // (float)hv[c] is exact (+-1); fpext+fma folds to v_fma_mix_f32.
    for (int jb = 0; jb < kN / 8; ++jb) {
      float jv[8];
#pragma unroll
      for (int c = 0; c < 8; ++c) jv[c] = jsym[(jb * 8 + c) * kN + i];
      half8 hv[kSamp];
#pragma unroll
      for (int g = 0; g < kSamp; ++g)
        hv[g] = *(const half8*)&sh16[g][jb * 8];
#pragma unroll
      for (int c = 0; c < 8; ++c) {
#pragma unroll
        for (int g = 0; g < kSamp; ++g)
          acc[g] = fmaf((float)hv[g][c], jv[c], acc[g]);
      }
    }
    __syncthreads();   // all reads of sh16 done

    const uint32_t k1a = g_keys.sk[t][0], k1b = g_keys.sk[t][1];
    const uint32_t k2a = g_keys.sk[t][2], k2b = g_keys.sk[t][3];
#pragma unroll
    for (int g = 0; g < kSamp; ++g) {
      float s = sreg[g];
      float local = th[g] + acc[g];
      float dE = -2.0f * s * local;
      float p = expf(-beta * dE);
      uint32_t m = (uint32_t)((b0 + g) * kN + i);
      float u1 = bits_to_uniform(rng_bits32(k1a, k1b, m));
      float u2 = bits_to_uniform(rng_bits32(k2a, k2b, m));
      if ((u1 < p) && (u2 < 0.5f)) s = -s;
      sreg[g] = s;
      sh16[g][i] = (_Float16)s;
    }
    __syncthreads();   // writes visible before next sweep's reads
  }

  // Epilogue: one more exact chain pass on the final state.
  float acc[kSamp];
#pragma unroll
  for (int g = 0; g < kSamp; ++g) acc[g] = 0.0f;
  for (int jb = 0; jb < kN / 8; ++jb) {
    float jv[8];
#pragma unroll
    for (int c = 0; c < 8; ++c) jv[c] = jsym[(jb * 8 + c) * kN + i];
    half8 hv[kSamp];
#pragma unroll
    for (int g = 0; g < kSamp; ++g)
      hv[g] = *(const half8*)&sh16[g][jb * 8];
#pragma unroll
    for (int c = 0; c < 8; ++c) {
#pragma unroll
      for (int g = 0; g < kSamp; ++g)
        acc[g] = fmaf((float)hv[g][c], jv[c], acc[g]);
    }
  }

  const int lane = threadIdx.x & 63;
  const int wid = threadIdx.x >> 6;
#pragma unroll
  for (int g = 0; g < kSamp; ++g) {
    float v = sreg[g] * th[g] + 0.5f * (sreg[g] * acc[g]);
#pragma unroll
    for (int off = 32; off > 0; off >>= 1) v += __shfl_down(v, off);
    if (lane == 0) sh_red[g][wid] = v;
  }
  __syncthreads();
  if (threadIdx.x < kSamp) {
    int g = threadIdx.x;
    out[b0 + g] = sh_red[g][0] + sh_red[g][1] + sh_red[g][2] + sh_red[g][3];
  }
}

}  // namespace

extern "C" void kernel_launch(void* const* d_in, const int* in_sizes, int n_in,
                              void* d_out, int out_size, void* d_ws, size_t ws_size,
                              hipStream_t stream) {
  const float* thetas = (const float*)d_in[0];   // [4096, 256]
  const float* gamma  = (const float*)d_in[1];   // [256, 256]
  float* jsym  = (float*)d_ws;                   // 256 KiB
  float* betas = (float*)((char*)d_ws + kN * kN * sizeof(float));

  hipLaunchKernelGGL(prep_kernel, dim3(kN), dim3(kN), 0, stream, gamma, jsym, betas);
  hipLaunchKernelGGL(anneal_kernel, dim3(kBlocks), dim3(256), 0, stream,
                     thetas, jsym, betas, (float*)d_out);
}

// Round 5
// 3656.441 us; speedup vs baseline: 1.0194x; 1.0194x over previous
//
#include <hip/hip_runtime.h>
#include <stdint.h>
#include <math.h>

// jax.random threefry2x32, partitionable mode — verified bit-exact (rounds 1,3:
// absmax 0.0). DO NOT change any arithmetic in the decision chain: the fp32
// fmaf chain order j=0..255, expf, compares are load-bearing (round 2 proved
// even a correctly-rounded f64 field diverges: absmax 10 > 8.16).
// Round 4 failed on a J4 stride bug (group stride is 256 float4s, used 64) —
// fixed here; arithmetic identical to round 3.
#define PARTITIONABLE 1

namespace {

constexpr int kB = 4096;
constexpr int kN = 256;
constexpr int kSweeps = 200;
constexpr int kSamp = 4;                 // samples per block
constexpr int kBlocks = kB / kSamp;      // 1024 blocks -> 4 blocks/CU, 16 waves/CU
constexpr int kGrpF4 = kN;               // float4s per j-group of 4: kN*4/4 = 256

typedef _Float16 half8 __attribute__((ext_vector_type(8)));

struct K2 { uint32_t a, b; };

__host__ __device__ constexpr uint32_t crotl(uint32_t x, int d) {
  return (x << d) | (x >> (32 - d));
}

__host__ __device__ constexpr K2 ctf(uint32_t k0, uint32_t k1, uint32_t c0, uint32_t c1) {
  uint32_t ks0 = k0, ks1 = k1, ks2 = k0 ^ k1 ^ 0x1BD11BDAu;
  uint32_t x0 = c0 + ks0, x1 = c1 + ks1;
  const int r0[4] = {13, 15, 26, 6};
  const int r1[4] = {17, 29, 16, 24};
  for (int i = 0; i < 4; ++i) { x0 += x1; x1 = crotl(x1, r0[i]); x1 ^= x0; }
  x0 += ks1; x1 += ks2 + 1u;
  for (int i = 0; i < 4; ++i) { x0 += x1; x1 = crotl(x1, r1[i]); x1 ^= x0; }
  x0 += ks2; x1 += ks0 + 2u;
  for (int i = 0; i < 4; ++i) { x0 += x1; x1 = crotl(x1, r0[i]); x1 ^= x0; }
  x0 += ks0; x1 += ks1 + 3u;
  for (int i = 0; i < 4; ++i) { x0 += x1; x1 = crotl(x1, r1[i]); x1 ^= x0; }
  x0 += ks1; x1 += ks2 + 4u;
  for (int i = 0; i < 4; ++i) { x0 += x1; x1 = crotl(x1, r0[i]); x1 ^= x0; }
  x0 += ks2; x1 += ks0 + 5u;
  return K2{x0, x1};
}

struct KeyTable {
  uint32_t s0k[2];
  uint32_t sk[kSweeps][4];   // per sweep: k1a,k1b (accept), k2a,k2b (mask)
};

constexpr KeyTable make_keys() {
  KeyTable t{};
  K2 root{0u, 42u};
#if PARTITIONABLE
  K2 k0 = ctf(root.a, root.b, 0u, 0u);
  K2 kl = ctf(root.a, root.b, 0u, 1u);
#else
  K2 p0 = ctf(root.a, root.b, 0u, 2u);
  K2 p1 = ctf(root.a, root.b, 1u, 3u);
  K2 k0{p0.a, p1.a};
  K2 kl{p0.b, p1.b};
#endif
  t.s0k[0] = k0.a; t.s0k[1] = k0.b;
  K2 k = kl;
  for (int s = 0; s < kSweeps; ++s) {
#if PARTITIONABLE
    K2 kn = ctf(k.a, k.b, 0u, 0u);
    K2 k1 = ctf(k.a, k.b, 0u, 1u);
    K2 k2 = ctf(k.a, k.b, 0u, 2u);
#else
    K2 q0 = ctf(k.a, k.b, 0u, 3u);
    K2 q1 = ctf(k.a, k.b, 1u, 4u);
    K2 q2 = ctf(k.a, k.b, 2u, 5u);
    K2 kn{q0.a, q1.a};
    K2 k1{q2.a, q0.b};
    K2 k2{q1.b, q2.b};
#endif
    t.sk[s][0] = k1.a; t.sk[s][1] = k1.b;
    t.sk[s][2] = k2.a; t.sk[s][3] = k2.b;
    k = kn;
  }
  return t;
}

__constant__ KeyTable g_keys = make_keys();

__device__ __forceinline__ uint32_t rng_bits32(uint32_t ka, uint32_t kb, uint32_t m) {
#if PARTITIONABLE
  K2 r = ctf(ka, kb, 0u, m);
  return r.a ^ r.b;
#else
  constexpr uint32_t H = (uint32_t)(kB * kN / 2);
  uint32_t p = (m < H) ? m : (m - H);
  K2 r = ctf(ka, kb, p, p + H);
  return (m < H) ? r.a : r.b;
#endif
}

__device__ __forceinline__ float bits_to_uniform(uint32_t bits) {
  return __uint_as_float((bits >> 9) | 0x3f800000u) - 1.0f;
}

// J4 layout: J4[(j>>2)*1024 + i*4 + (j&3)] = Jsym[j][i] = J[i][j].
// Thread i reads its 4 consecutive-j column values as one dwordx4,
// coalesced across lanes (16B/lane, 1KB/wave contiguous).
__global__ void prep_kernel(const float* __restrict__ gamma,
                            float* __restrict__ j4,
                            float* __restrict__ betas) {
  int e = blockIdx.x * blockDim.x + threadIdx.x;   // 0..65535
  int j = e / kN, i = e % kN;                      // Jsym[j][i]
  float v = 0.0f;
  if (j < i) v = gamma[j * kN + i];
  else if (j > i) v = gamma[i * kN + j];
  j4[(j >> 2) * (kN * 4) + i * 4 + (j & 3)] = v;
  if (e < kSweeps) {
    double l0 = log(0.1), l1 = log(5.0);
    betas[e] = (float)exp(l0 + (l1 - l0) * (double)e / (double)(kSweeps - 1));
  }
}

__global__ __launch_bounds__(256) void anneal_kernel(
    const float* __restrict__ thetas, const float* __restrict__ j4,
    const float* __restrict__ betas, float* __restrict__ out) {
  // s as f16 (+-1.0 exact): one ds_read_b128 delivers 8 j per sample.
  __shared__ __align__(16) _Float16 sh16[kSamp][kN];
  __shared__ float sh_red[kSamp][4];

  const int i = threadIdx.x;           // spin index (lane+wave)
  const int b0 = blockIdx.x * kSamp;

  float th[kSamp], sreg[kSamp];
#pragma unroll
  for (int g = 0; g < kSamp; ++g) th[g] = thetas[(b0 + g) * kN + i];

#pragma unroll
  for (int g = 0; g < kSamp; ++g) {
    uint32_t m = (uint32_t)((b0 + g) * kN + i);
    float u = bits_to_uniform(rng_bits32(g_keys.s0k[0], g_keys.s0k[1], m));
    float sv = (u < 0.5f) ? 1.0f : -1.0f;
    sreg[g] = sv;
    sh16[g][i] = (_Float16)sv;
  }
  __syncthreads();

  // Per-thread column base: quad for j-group g4 sits at jcol[g4 * kGrpF4].
  const float4* __restrict__ jcol = (const float4*)(j4 + i * 4);

  for (int t = 0; t < kSweeps; ++t) {
    const float beta = betas[t];

    float acc[kSamp];
#pragma unroll
    for (int g = 0; g < kSamp; ++g) acc[g] = 0.0f;

    // Chain: acc_i = sum_j J[i][j]*s[j], j ascending, one fp32 fma per term.
    // (float)hv[c] is exact (+-1); fpext+fma folds to v_fma_mix_f32.
    for (int jb = 0; jb < kN / 8; ++jb) {
      float4 ja = jcol[(2 * jb + 0) * kGrpF4];   // j = jb*8+0..3
      float4 jbv = jcol[(2 * jb + 1) * kGrpF4];  // j = jb*8+4..7
      float jv[8] = {ja.x, ja.y, ja.z, ja.w, jbv.x, jbv.y, jbv.z, jbv.w};
      half8 hv[kSamp];
#pragma unroll
      for (int g = 0; g < kSamp; ++g)
        hv[g] = *(const half8*)&sh16[g][jb * 8];
#pragma unroll
      for (int c = 0; c < 8; ++c) {
#pragma unroll
        for (int g = 0; g < kSamp; ++g)
          acc[g] = fmaf((float)hv[g][c], jv[c], acc[g]);
      }
    }
    __syncthreads();   // all reads of sh16 done

    const uint32_t k1a = g_keys.sk[t][0], k1b = g_keys.sk[t][1];
    const uint32_t k2a = g_keys.sk[t][2], k2b = g_keys.sk[t][3];
#pragma unroll
    for (int g = 0; g < kSamp; ++g) {
      float s = sreg[g];
      float local = th[g] + acc[g];
      float dE = -2.0f * s * local;
      float p = expf(-beta * dE);
      uint32_t m = (uint32_t)((b0 + g) * kN + i);
      float u1 = bits_to_uniform(rng_bits32(k1a, k1b, m));
      float u2 = bits_to_uniform(rng_bits32(k2a, k2b, m));
      if ((u1 < p) && (u2 < 0.5f)) s = -s;
      sreg[g] = s;
      sh16[g][i] = (_Float16)s;
    }
    __syncthreads();   // writes visible before next sweep's reads
  }

  // Epilogue: one more exact chain pass on the final state.
  float acc[kSamp];
#pragma unroll
  for (int g = 0; g < kSamp; ++g) acc[g] = 0.0f;
  for (int jb = 0; jb < kN / 8; ++jb) {
    float4 ja = jcol[(2 * jb + 0) * kGrpF4];
    float4 jbv = jcol[(2 * jb + 1) * kGrpF4];
    float jv[8] = {ja.x, ja.y, ja.z, ja.w, jbv.x, jbv.y, jbv.z, jbv.w};
    half8 hv[kSamp];
#pragma unroll
    for (int g = 0; g < kSamp; ++g)
      hv[g] = *(const half8*)&sh16[g][jb * 8];
#pragma unroll
    for (int c = 0; c < 8; ++c) {
#pragma unroll
      for (int g = 0; g < kSamp; ++g)
        acc[g] = fmaf((float)hv[g][c], jv[c], acc[g]);
    }
  }

  const int lane = threadIdx.x & 63;
  const int wid = threadIdx.x >> 6;
#pragma unroll
  for (int g = 0; g < kSamp; ++g) {
    float v = sreg[g] * th[g] + 0.5f * (sreg[g] * acc[g]);
#pragma unroll
    for (int off = 32; off > 0; off >>= 1) v += __shfl_down(v, off);
    if (lane == 0) sh_red[g][wid] = v;
  }
  __syncthreads();
  if (threadIdx.x < kSamp) {
    int g = threadIdx.x;
    out[b0 + g] = sh_red[g][0] + sh_red[g][1] + sh_red[g][2] + sh_red[g][3];
  }
}

}  // namespace

extern "C" void kernel_launch(void* const* d_in, const int* in_sizes, int n_in,
                              void* d_out, int out_size, void* d_ws, size_t ws_size,
                              hipStream_t stream) {
  const float* thetas = (const float*)d_in[0];   // [4096, 256]
  const float* gamma  = (const float*)d_in[1];   // [256, 256]
  float* j4    = (float*)d_ws;                   // 256 KiB, J4 layout
  float* betas = (float*)((char*)d_ws + kN * kN * sizeof(float));

  hipLaunchKernelGGL(prep_kernel, dim3(kN), dim3(kN), 0, stream, gamma, j4, betas);
  hipLaunchKernelGGL(anneal_kernel, dim3(kBlocks), dim3(256), 0, stream,
                     thetas, j4, betas, (float*)d_out);
}